// Round 4
// baseline (316.595 us; speedup 1.0000x reference)
//
#include <hip/hip_runtime.h>

// Inverse 2-level orthonormal Haar DWT with zero details ==
// 4x4 nearest-neighbor upsample scaled by 1/4.
// in : [B=128, C=3, 128, 128] f32 (flat)
// out: [B=128, C=3, 512, 512] f32 (flat)
//
// One thread = 16 consecutive output floats (4 nt float4 stores) in one row.
// Those come from 4 consecutive input pixels = one aligned float4 load.
// Lane i -> consecutive 64B chunk: stores are 4 KB/wave, globally monotone
// (fill-kernel shape, 6.8 TB/s ceiling); loads are 1 KB/wave coalesced.
// nt stores keep the 403 MB write stream evict-first in L2 so the 25 MB
// input (re-read 4x, once per output-row group) stays cached.
// Exact grid, no loop: out 25165824 float4 / 4 per thread / 256 = 24576 blocks.

typedef float f32x4 __attribute__((ext_vector_type(4)));

__global__ void __launch_bounds__(256) haar_upsample4_kernel(
        const f32x4* __restrict__ z4, float* __restrict__ out) {
    const int j = blockIdx.x * 256 + threadIdx.x;   // 0 .. 6291455
    // j indexes a 16-float (4 x float4) chunk of the output.
    // output row = 128 float4 = 32 chunks
    const int w16  = j & 31;         // chunk within row -> input float4 index in row
    const int rest = j >> 5;
    const int h    = rest & 511;
    const int bc   = rest >> 9;      // b*C + c, < 384
    const int h_in = h >> 2;

    // input row = 128 floats = 32 float4
    const f32x4 in = z4[(bc << 12) + (h_in << 5) + w16];

    const f32x4 o0 = {in.x * 0.25f, in.x * 0.25f, in.x * 0.25f, in.x * 0.25f};
    const f32x4 o1 = {in.y * 0.25f, in.y * 0.25f, in.y * 0.25f, in.y * 0.25f};
    const f32x4 o2 = {in.z * 0.25f, in.z * 0.25f, in.z * 0.25f, in.z * 0.25f};
    const f32x4 o3 = {in.w * 0.25f, in.w * 0.25f, in.w * 0.25f, in.w * 0.25f};

    f32x4* o = reinterpret_cast<f32x4*>(out) + ((size_t)j << 2);
    __builtin_nontemporal_store(o0, o + 0);
    __builtin_nontemporal_store(o1, o + 1);
    __builtin_nontemporal_store(o2, o + 2);
    __builtin_nontemporal_store(o3, o + 3);
}

extern "C" void kernel_launch(void* const* d_in, const int* in_sizes, int n_in,
                              void* d_out, int out_size, void* d_ws, size_t ws_size,
                              hipStream_t stream) {
    const f32x4* z4 = (const f32x4*)d_in[0];
    float* out = (float*)d_out;
    const int threads = out_size / 16;       // 6,291,456
    const int grid = threads / 256;          // 24,576
    haar_upsample4_kernel<<<grid, 256, 0, stream>>>(z4, out);
}

// Round 5
// 75.237 us; speedup vs baseline: 4.2079x; 4.2079x over previous
//
#include <hip/hip_runtime.h>

// Inverse 2-level orthonormal Haar DWT with zero details ==
// 4x4 nearest-neighbor upsample scaled by 1/4.
// in : [B=128, C=3, 128, 128] f32 (flat)
// out: [B=128, C=3, 512, 512] f32 (flat)
//
// Lesson from R4: per-INSTRUCTION wave footprint must be contiguous.
// Block = 1024 consecutive output float4s (16 KB). Thread t stores float4s
// at base + t + k*256 (k=0..3): each store instruction is 64 lanes x 16 B
// = 1 KB contiguous (full sectors, no RMW amplification), and the 4 stores
// per thread are independent chains (store ILP). Input pixel column
// w4 = t & 127 is constant across k; 4 scalar loads, 256 B/wave coalesced.
// nt stores keep the 403 MB stream evict-first; input re-reads hit L2/L3.

typedef float f32x4 __attribute__((ext_vector_type(4)));

__global__ void __launch_bounds__(256) haar_upsample4_kernel(
        const float* __restrict__ z, float* __restrict__ out) {
    const int t    = threadIdx.x;
    const int base = blockIdx.x << 10;        // 1024 float4s per block
    const int w4   = t & 127;                 // input pixel column
    const int r0   = (base >> 7) + (t >> 7);  // j>>7 for k=0

    float v[4];
    #pragma unroll
    for (int k = 0; k < 4; ++k) {
        // j = base + k*256 + t ; rest = j>>7 = r0 + 2k ; w4 = j&127 = t&127
        const int rest = r0 + (k << 1);
        const int h    = rest & 511;          // output row
        const int bc   = rest >> 9;           // b*C + c, < 384
        const int h_in = h >> 2;
        v[k] = z[(bc << 14) + (h_in << 7) + w4] * 0.25f;
    }

    f32x4* o = reinterpret_cast<f32x4*>(out) + base + t;
    #pragma unroll
    for (int k = 0; k < 4; ++k) {
        const f32x4 o4 = {v[k], v[k], v[k], v[k]};
        __builtin_nontemporal_store(o4, o + (k << 8));
    }
}

extern "C" void kernel_launch(void* const* d_in, const int* in_sizes, int n_in,
                              void* d_out, int out_size, void* d_ws, size_t ws_size,
                              hipStream_t stream) {
    const float* z = (const float*)d_in[0];
    float* out = (float*)d_out;
    const int total4 = out_size >> 2;        // 8,388,608 float4s
    const int grid = total4 >> 10;           // 8192 blocks (exact)
    haar_upsample4_kernel<<<grid, 256, 0, stream>>>(z, out);
}

// Round 6
// 70.387 us; speedup vs baseline: 4.4979x; 1.0689x over previous
//
#include <hip/hip_runtime.h>

// Inverse 2-level orthonormal Haar DWT with zero details ==
// 4x4 nearest-neighbor upsample scaled by 1/4.
// in : [B=128, C=3, 128, 128] f32 (flat)
// out: [B=128, C=3, 512, 512] f32 (flat)
//
// R6 = within-round A/B on store cache policy (the one variable separating us
// from the 86%-of-peak fillBuffer kernel). Same R5 structure for both halves:
// block = 1024 consecutive output float4s, thread t stores at base + t + k*256
// (each store instruction 1 KB wave-contiguous, no RMW amplification).
// Kernel A (blocks [0,4096))  : non-temporal stores  -> first  half of out.
// Kernel B (blocks [4096,8192)): plain stores (L2)   -> second half of out.
// Each dispatch is profiled separately: compare dur_us / hbm_gbps / WRITE_SIZE.

typedef float f32x4 __attribute__((ext_vector_type(4)));

template <bool NT>
__global__ void __launch_bounds__(256) haar_upsample4_kernel(
        const float* __restrict__ z, float* __restrict__ out, int block_base) {
    const int t    = threadIdx.x;
    const int blk  = blockIdx.x + block_base;
    const int base = blk << 10;               // 1024 float4s per block
    const int w4   = t & 127;                 // input pixel column
    const int r0   = (base >> 7) + (t >> 7);  // j>>7 for k=0

    float v[4];
    #pragma unroll
    for (int k = 0; k < 4; ++k) {
        // j = base + k*256 + t ; rest = j>>7 = r0 + 2k ; w4 = j&127 = t&127
        const int rest = r0 + (k << 1);
        const int h    = rest & 511;          // output row
        const int bc   = rest >> 9;           // b*C + c, < 384
        const int h_in = h >> 2;
        v[k] = z[(bc << 14) + (h_in << 7) + w4] * 0.25f;
    }

    f32x4* o = reinterpret_cast<f32x4*>(out) + base + t;
    #pragma unroll
    for (int k = 0; k < 4; ++k) {
        const f32x4 o4 = {v[k], v[k], v[k], v[k]};
        if constexpr (NT) {
            __builtin_nontemporal_store(o4, o + (k << 8));
        } else {
            o[k << 8] = o4;
        }
    }
}

extern "C" void kernel_launch(void* const* d_in, const int* in_sizes, int n_in,
                              void* d_out, int out_size, void* d_ws, size_t ws_size,
                              hipStream_t stream) {
    const float* z = (const float*)d_in[0];
    float* out = (float*)d_out;
    const int total4 = out_size >> 2;        // 8,388,608 float4s
    const int grid   = total4 >> 10;         // 8192 blocks total
    const int half   = grid >> 1;            // 4096 per variant

    haar_upsample4_kernel<true ><<<half, 256, 0, stream>>>(z, out, 0);
    haar_upsample4_kernel<false><<<half, 256, 0, stream>>>(z, out, half);
}